// Round 2
// baseline (119.156 us; speedup 1.0000x reference)
//
#include <hip/hip_runtime.h>

#define IMG_W 512
#define NB 32

// ---------------- X: cumsum along width (contiguous axis) ----------------
// One wave per row, single pass: lane i owns elements [4i..4i+3] of the first
// 256 and [256+4i..256+4i+3] of the second 256. Two INDEPENDENT 6-step
// shfl_up scans (ILP-overlapped), one broadcast joins them — no serial carry.
__device__ __forceinline__ void row_cumsum_wave(const float* __restrict__ in,
                                                float* __restrict__ out,
                                                int gwave) {
    const int lane = threadIdx.x & 63;
    const int b = gwave >> 9;          // gwave / 512
    const int row = gwave & 511;
    const long base = ((long)(b * 2 + 0) * IMG_W + row) * IMG_W;

    const float4 va = *reinterpret_cast<const float4*>(in + base + lane * 4);
    const float4 vb = *reinterpret_cast<const float4*>(in + base + 256 + lane * 4);

    // in-lane inclusive prefixes
    const float a0 = va.x, a1 = a0 + va.y, a2 = a1 + va.z, a3 = a2 + va.w;
    const float b0 = vb.x, b1 = b0 + vb.y, b2 = b1 + vb.z, b3 = b2 + vb.w;

    // two independent wave-inclusive scans of lane totals
    float ta = a3, tb = b3;
#pragma unroll
    for (int d = 1; d < 64; d <<= 1) {
        const float ua = __shfl_up(ta, d);
        const float ub = __shfl_up(tb, d);
        if (lane >= d) { ta += ua; tb += ub; }
    }
    const float totalA = __shfl(ta, 63);
    const float exA = ta - a3;            // sum of first-half elements before this lane
    const float exB = totalA + (tb - b3); // offset for second half

    float4 oa, ob;
    oa.x = exA + a0; oa.y = exA + a1; oa.z = exA + a2; oa.w = exA + a3;
    ob.x = exB + b0; ob.y = exB + b1; ob.z = exB + b2; ob.w = exB + b3;
    *reinterpret_cast<float4*>(out + base + lane * 4) = oa;
    *reinterpret_cast<float4*>(out + base + 256 + lane * 4) = ob;
}

// ---------------- Y: cumsum along height (stride-IMG_W axis) ----------------
// Reduce-then-scan, S segments of ROWS = 512/S rows, float4 per thread
// (4 consecutive columns -> 16 B/lane, 1 KiB per wave-access).

template <int S>
__global__ __launch_bounds__(256) void k1_fused(const float* __restrict__ in,
                                                float* __restrict__ out,
                                                float* __restrict__ ws,
                                                int yblocksA) {
    constexpr int ROWS = IMG_W / S;
    if ((int)blockIdx.x < yblocksA) {
        // ---- Y phase A: per-segment column sums (2 segments per block) ----
        const int yb = blockIdx.x;
        const int b = yb / (S / 2);
        const int sp = yb % (S / 2);
        const int s = sp * 2 + (threadIdx.x >> 7);   // 2 segs per 256-thread block
        const int grp = threadIdx.x & 127;           // float4 column group
        const long ibase = ((long)(b * 2 + 1) * IMG_W + (long)s * ROWS) * IMG_W + grp * 4;
        float4 acc = make_float4(0.f, 0.f, 0.f, 0.f);
#pragma unroll
        for (int r = 0; r < ROWS; ++r) {
            const float4 v = *reinterpret_cast<const float4*>(in + ibase + (long)r * IMG_W);
            acc.x += v.x; acc.y += v.y; acc.z += v.z; acc.w += v.w;
        }
        *reinterpret_cast<float4*>(ws + ((long)b * S + s) * IMG_W + grp * 4) = acc;
    } else {
        // ---- X work: 4 waves per block, one row per wave ----
        const int gwave = (blockIdx.x - yblocksA) * 4 + (threadIdx.x >> 6);
        row_cumsum_wave(in, out, gwave);
    }
}

template <int S>
__global__ __launch_bounds__(128) void k2_scan(const float* __restrict__ in,
                                               float* __restrict__ out,
                                               const float* __restrict__ ws) {
    constexpr int ROWS = IMG_W / S;
    const int yb = blockIdx.x;                 // [0, NB*S)
    const int b = yb / S;
    const int s = yb % S;
    const int grp = threadIdx.x;               // 0..127, 4 cols each

    // offset = sum of totals of preceding segments (coalesced float4 reads)
    float4 acc = make_float4(0.f, 0.f, 0.f, 0.f);
    for (int u = 0; u < s; ++u) {
        const float4 w = *reinterpret_cast<const float4*>(ws + ((long)b * S + u) * IMG_W + grp * 4);
        acc.x += w.x; acc.y += w.y; acc.z += w.z; acc.w += w.w;
    }

    const long ibase = ((long)(b * 2 + 1) * IMG_W + (long)s * ROWS) * IMG_W + grp * 4;
#pragma unroll
    for (int r = 0; r < ROWS; ++r) {
        const float4 v = *reinterpret_cast<const float4*>(in + ibase + (long)r * IMG_W);
        acc.x += v.x; acc.y += v.y; acc.z += v.z; acc.w += v.w;
        *reinterpret_cast<float4*>(out + ibase + (long)r * IMG_W) = acc;
    }
}

template <int S>
static void launch_impl(const float* in, float* out, float* ws, hipStream_t stream) {
    const int yblocksA = NB * (S / 2);             // phase A blocks (256 thr, 2 segs each)
    const int xblocks = (NB * IMG_W) / 4;          // 4096 blocks (4 rows/block)
    k1_fused<S><<<yblocksA + xblocks, 256, 0, stream>>>(in, out, ws, yblocksA);
    k2_scan<S><<<NB * S, 128, 0, stream>>>(in, out, ws);
}

extern "C" void kernel_launch(void* const* d_in, const int* in_sizes, int n_in,
                              void* d_out, int out_size, void* d_ws, size_t ws_size,
                              hipStream_t stream) {
    const float* in = (const float*)d_in[0];
    float* out = (float*)d_out;
    float* ws = (float*)d_ws;

    // ws need: NB * S * IMG_W floats
    const size_t per_seg = (size_t)NB * IMG_W * sizeof(float);  // 64 KiB per segment
    if (ws_size >= 32 * per_seg)      launch_impl<32>(in, out, ws, stream);
    else if (ws_size >= 16 * per_seg) launch_impl<16>(in, out, ws, stream);
    else                              launch_impl<8>(in, out, ws, stream);
}

// Round 3
// 111.150 us; speedup vs baseline: 1.0720x; 1.0720x over previous
//
#include <hip/hip_runtime.h>

#define IMG_W 512
#define NB 32

#define YBLOCKS (NB * 8)   // 8 column-groups of 64 per image
#define XBLOCKS 1024       // 16384 rows / 16 waves per block
#define THREADS 1024
#define SEGS 16
#define ROWSEG 32          // 512 / SEGS
#define COLS 64
#define TILE_FLOATS (IMG_W * COLS)                 // 32768 (128 KiB)
#define LDS_FLOATS (TILE_FLOATS + 2 * SEGS * COLS) // + tot + off (4 KiB)

// ---------------- X: cumsum along width (contiguous axis) ----------------
// One wave per row, single pass: two independent 6-step shfl_up scans over
// the two 256-element halves, joined by one broadcast.
__device__ __forceinline__ void row_cumsum_wave(const float* __restrict__ in,
                                                float* __restrict__ out,
                                                int gwave) {
    const int lane = threadIdx.x & 63;
    const int b = gwave >> 9;
    const int row = gwave & 511;
    const long base = ((long)(b * 2 + 0) * IMG_W + row) * IMG_W;

    const float4 va = *reinterpret_cast<const float4*>(in + base + lane * 4);
    const float4 vb = *reinterpret_cast<const float4*>(in + base + 256 + lane * 4);

    const float a0 = va.x, a1 = a0 + va.y, a2 = a1 + va.z, a3 = a2 + va.w;
    const float b0 = vb.x, b1 = b0 + vb.y, b2 = b1 + vb.z, b3 = b2 + vb.w;

    float ta = a3, tb = b3;
#pragma unroll
    for (int d = 1; d < 64; d <<= 1) {
        const float ua = __shfl_up(ta, d);
        const float ub = __shfl_up(tb, d);
        if (lane >= d) { ta += ua; tb += ub; }
    }
    const float totalA = __shfl(ta, 63);
    const float exA = ta - a3;
    const float exB = totalA + (tb - b3);

    float4 oa, ob;
    oa.x = exA + a0; oa.y = exA + a1; oa.z = exA + a2; oa.w = exA + a3;
    ob.x = exB + b0; ob.y = exB + b1; ob.z = exB + b2; ob.w = exB + b3;
    *reinterpret_cast<float4*>(out + base + lane * 4) = oa;
    *reinterpret_cast<float4*>(out + base + 256 + lane * 4) = ob;
}

// ---------------- fused single-dispatch kernel ----------------
// Blocks [0, YBLOCKS): Y cumsum, single pass via LDS tile.
// Blocks [YBLOCKS, ...): X cumsum, one row per wave (16 waves/block).
extern "C" __global__ __launch_bounds__(THREADS)
void gsi_fused(const float* __restrict__ in, float* __restrict__ out) {
    extern __shared__ float lds[];
    const int tid = threadIdx.x;

    if ((int)blockIdx.x < YBLOCKS) {
        float* tot = lds + TILE_FLOATS;
        float* off = tot + SEGS * COLS;
        const int b = blockIdx.x >> 3;
        const int colg = blockIdx.x & 7;
        const long ybase = ((long)(b * 2 + 1) * IMG_W) * IMG_W + colg * COLS;

        // stage 512x64 tile: float4 coalesced (wave = 4 rows x 256B)
#pragma unroll
        for (int it = 0; it < 8; ++it) {
            const int idx = it * THREADS + tid;
            const int row = idx >> 4;
            const int c4 = idx & 15;
            const float4 v = *reinterpret_cast<const float4*>(
                in + ybase + (long)row * IMG_W + c4 * 4);
            *reinterpret_cast<float4*>(lds + row * COLS + c4 * 4) = v;
        }
        __syncthreads();

        // per-segment serial scan in LDS (wave lanes -> consecutive banks)
        const int col = tid & 63;
        const int seg = tid >> 6;
        const int rbase = seg * ROWSEG;
        float acc = 0.f;
#pragma unroll
        for (int r = 0; r < ROWSEG; ++r) {
            const int a = (rbase + r) * COLS + col;
            acc += lds[a];
            lds[a] = acc;
        }
        tot[seg * COLS + col] = acc;
        __syncthreads();

        // per-(seg,col) exclusive offset over segment totals
        float o = 0.f;
        for (int u = 0; u < seg; ++u) o += tot[u * COLS + col];
        off[seg * COLS + col] = o;
        __syncthreads();

        // writeback: float4 coalesced, add per-segment column offsets
#pragma unroll
        for (int it = 0; it < 8; ++it) {
            const int idx = it * THREADS + tid;
            const int row = idx >> 4;
            const int c4 = idx & 15;
            const int sg = row >> 5;  // ROWSEG = 32
            const float4 v = *reinterpret_cast<const float4*>(lds + row * COLS + c4 * 4);
            const float4 o4 = *reinterpret_cast<const float4*>(off + sg * COLS + c4 * 4);
            float4 w;
            w.x = v.x + o4.x; w.y = v.y + o4.y; w.z = v.z + o4.z; w.w = v.w + o4.w;
            *reinterpret_cast<float4*>(out + ybase + (long)row * IMG_W + c4 * 4) = w;
        }
    } else {
        const int gwave = ((int)blockIdx.x - YBLOCKS) * 16 + (tid >> 6);
        row_cumsum_wave(in, out, gwave);
    }
}

extern "C" void kernel_launch(void* const* d_in, const int* in_sizes, int n_in,
                              void* d_out, int out_size, void* d_ws, size_t ws_size,
                              hipStream_t stream) {
    const float* in = (const float*)d_in[0];
    float* out = (float*)d_out;
    const int lds_bytes = LDS_FLOATS * 4;  // 136 KiB (<= 160 KiB/CU)

    (void)hipFuncSetAttribute(reinterpret_cast<const void*>(gsi_fused),
                              hipFuncAttributeMaxDynamicSharedMemorySize, lds_bytes);
    gsi_fused<<<YBLOCKS + XBLOCKS, THREADS, lds_bytes, stream>>>(in, out);
}